// Round 1
// 967.099 us; speedup vs baseline: 1.1159x; 1.1159x over previous
//
#include <hip/hip_runtime.h>
#include <stdint.h>

// Problem constants (fixed by the reference).
#define Bn 2
#define Hn 16
#define Sn 2048
#define Dn 64
#define TQ 16                  // q rows per workgroup (each wave: all its 2 heads x 16 q)
#define KSPLIT 8               // k-range split across workgroups
#define KRANGE (Sn / KSPLIT)   // 256
#define KITER 32               // k columns per iteration (full K=32 PV MFMA)
#define NITER (KRANGE / KITER) // 8

typedef __attribute__((ext_vector_type(8))) short short8;
typedef __attribute__((ext_vector_type(4))) short short4v;
typedef __attribute__((ext_vector_type(4))) float float4v;

__device__ __forceinline__ short f2bf(float f) {
    uint32_t u = __builtin_bit_cast(uint32_t, f);
    u += 0x7fffu + ((u >> 16) & 1u);   // round-to-nearest-even
    return (short)(u >> 16);
}
__device__ __forceinline__ float bf2f(short s) {
    uint32_t u = ((uint32_t)(uint16_t)s) << 16;
    return __builtin_bit_cast(float, u);
}
// Load 8 consecutive fp32, convert to a bf16x8 MFMA fragment.
__device__ __forceinline__ short8 load_bf8(const float* p) {
    float4v a = *(const float4v*)p;
    float4v b = *(const float4v*)(p + 4);
    short8 r;
    r[0] = f2bf(a[0]); r[1] = f2bf(a[1]); r[2] = f2bf(a[2]); r[3] = f2bf(a[3]);
    r[4] = f2bf(b[0]); r[5] = f2bf(b[1]); r[6] = f2bf(b[2]); r[7] = f2bf(b[3]);
    return r;
}

#define MFMA(a, b, c) __builtin_amdgcn_mfma_f32_16x16x32_bf16((a), (b), (c), 0, 0, 0)

// Grid: 2048 blocks of 512 threads. Block = 8 waves; wave w owns heads {2w,2w+1}
// for a 16-row q tile and a 256-wide k range (split 8 ways, KITER=32 per step).
// Softmax is over the 16 heads at each (q,k): in-lane sum of the wave's 2 heads,
// then an 8-wave LDS reduction. Only TWO barriers per iteration; pbuf (bf16 attn
// staging for the PV A-fragment transpose) is wave-private -> no barrier needed.
// Register budget is sized for 4 waves/SIMD (2 resident blocks/CU) so barrier
// stalls of one block overlap the other block's compute.
__global__ __launch_bounds__(512, 4) void attn_fused(
    const float* __restrict__ Q, const float* __restrict__ K,
    const float* __restrict__ V, float* __restrict__ Out,
    float* __restrict__ Attn)
{
    // LDS: 8*32*20*2 + 32*20*4 + 8*16*40*2 = 10240 + 2560 + 10240 = 23040 B
    __shared__ short part[8][KITER][20];   // per-wave partial head-sums, [w][k][q+pad]
    __shared__ float den[KITER][20];       // softmax denominators, [k][q+pad]
    __shared__ short pbuf[8][TQ][40];      // per-wave attn bf16, [w][q][k+pad]

    // Bijective XCD swizzle (2048 = 8 * 256): each XCD gets a contiguous chunk,
    // i.e. 2 (b,ks) K/V panels (~4 MB) -> fits one XCD L2.
    const int bid0 = blockIdx.x;
    const int bid  = (bid0 & 7) * 256 + (bid0 >> 3);

    const int qb = bid & 127;        // consecutive swizzled ids share (b,ks) -> K/V L2 reuse
    const int t2 = bid >> 7;
    const int ks = t2 & 7;
    const int b  = t2 >> 3;

    const int tid  = threadIdx.x;
    const int wave = tid >> 6;
    const int lane = tid & 63;
    const int quad = lane >> 4;
    const int l16  = lane & 15;

    const int h0 = wave * 2;
    const int q0 = qb * TQ;
    const int k0 = ks * KRANGE;

    // Resident Q fragments: A[m=l16][k=quad*8+j] per (head, d-chunk of 32).
    short8 aq[2][2];
#pragma unroll
    for (int hi = 0; hi < 2; ++hi) {
        const float* qp = Q + ((size_t)(b * Hn + h0 + hi) * Sn + (size_t)(q0 + l16)) * Dn
                            + quad * 8;
        aq[hi][0] = load_bf8(qp);
        aq[hi][1] = load_bf8(qp + 32);
    }

    // Out accumulators: [head][d-chunk] 16x16 C-frags (q rows x 16 d cols).
    float4v acc[2][4];
#pragma unroll
    for (int hi = 0; hi < 2; ++hi)
#pragma unroll
        for (int dc = 0; dc < 4; ++dc)
            acc[hi][dc] = (float4v){0.f, 0.f, 0.f, 0.f};

    for (int it = 0; it < NITER; ++it) {
        const int kb = k0 + it * KITER;

        // --- QK^T -> e = exp(score/8), C-layout (q=quad*4+r, k=kk*16+l16) ---
        float4v e[2][2];
#pragma unroll
        for (int kk = 0; kk < 2; ++kk) {
            const size_t krow = (size_t)(kb + kk * 16 + l16);
            const float* kp0 = K + ((size_t)(b * Hn + h0)     * Sn + krow) * Dn + quad * 8;
            const float* kp1 = K + ((size_t)(b * Hn + h0 + 1) * Sn + krow) * Dn + quad * 8;
            short8 b00 = load_bf8(kp0);
            short8 b01 = load_bf8(kp0 + 32);
            short8 b10 = load_bf8(kp1);
            short8 b11 = load_bf8(kp1 + 32);
            float4v c0 = (float4v){0.f, 0.f, 0.f, 0.f};
            float4v c1 = (float4v){0.f, 0.f, 0.f, 0.f};
            c0 = MFMA(aq[0][0], b00, c0); c0 = MFMA(aq[0][1], b01, c0);
            c1 = MFMA(aq[1][0], b10, c1); c1 = MFMA(aq[1][1], b11, c1);
#pragma unroll
            for (int r = 0; r < 4; ++r) {
                e[0][kk][r] = __expf(c0[r] * 0.125f);
                e[1][kk][r] = __expf(c1[r] * 0.125f);
            }
            // per-wave head partial sums -> LDS (bf16, packed b64, 8B-aligned)
            float4v p = e[0][kk] + e[1][kk];
            short4v pb;
#pragma unroll
            for (int r = 0; r < 4; ++r) pb[r] = f2bf(p[r]);
            *(short4v*)&part[wave][kk * 16 + l16][quad * 4] = pb;
        }
        __syncthreads();   // [A] publish part

        // --- reduce over the 8 waves: 32k x 16q = 512 positions / 512 threads ---
        {
            const int kkr = tid >> 4;   // 0..31
            const int qq  = tid & 15;
            float s = 0.f;
#pragma unroll
            for (int w = 0; w < 8; ++w) s += bf2f(part[w][kkr][qq]);
            den[kkr][qq] = s;
        }
        __syncthreads();   // [B] publish den

        // --- attn = e / den ---
        float4v r4[2];
#pragma unroll
        for (int kk = 0; kk < 2; ++kk) {
            float4v d4 = *(const float4v*)&den[kk * 16 + l16][quad * 4];
#pragma unroll
            for (int r = 0; r < 4; ++r) r4[kk][r] = __builtin_amdgcn_rcpf(d4[r]);
        }

        // --- per head: NT-store attn, bf16 into wave-private pbuf, then PV ---
#pragma unroll
        for (int hi = 0; hi < 2; ++hi) {
            const int h = h0 + hi;
#pragma unroll
            for (int kk = 0; kk < 2; ++kk) {
                float4v a = e[hi][kk] * r4[kk];
                size_t base = ((size_t)(b * Hn + h) * Sn + (size_t)(q0 + quad * 4)) * Sn
                              + (size_t)(kb + kk * 16 + l16);
#pragma unroll
                for (int r = 0; r < 4; ++r) {
                    __builtin_nontemporal_store(a[r], Attn + base + (size_t)r * Sn);
                    pbuf[wave][quad * 4 + r][kk * 16 + l16] = f2bf(a[r]);
                }
            }
            // PV: out += P @ V with the FULL K=32 MFMA.
            // A-frag: one b128 read (wave-private pbuf; in-wave DS ordering suffices).
            short8 av = *(const short8*)&pbuf[wave][l16][quad * 8];
            const float* vbase = V + ((size_t)(b * Hn + h) * Sn + (size_t)(kb + quad * 8)) * Dn;
#pragma unroll
            for (int dc = 0; dc < 4; ++dc) {
                short8 bv;
#pragma unroll
                for (int j = 0; j < 8; ++j)
                    bv[j] = f2bf(vbase[(size_t)j * Dn + dc * 16 + l16]);
                acc[hi][dc] = MFMA(av, bv, acc[hi][dc]);
            }
        }
        // no 3rd barrier: part(i+1) writes are fenced by [B]; den(i+1) writes by [A].
    }

    // --- epilogue: atomic-accumulate the k-split partials into Out ---
#pragma unroll
    for (int hi = 0; hi < 2; ++hi)
#pragma unroll
        for (int dc = 0; dc < 4; ++dc) {
            float* op = Out + ((size_t)(b * Hn + h0 + hi) * Sn + (size_t)(q0 + quad * 4)) * Dn
                        + dc * 16 + l16;
#pragma unroll
            for (int r = 0; r < 4; ++r)
                unsafeAtomicAdd(op + (size_t)r * Dn, acc[hi][dc][r]);
        }
}

extern "C" void kernel_launch(void* const* d_in, const int* in_sizes, int n_in,
                              void* d_out, int out_size, void* d_ws, size_t ws_size,
                              hipStream_t stream) {
    const float* q = (const float*)d_in[0];
    const float* k = (const float*)d_in[1];
    const float* v = (const float*)d_in[2];
    float* out  = (float*)d_out;
    float* attn = out + (size_t)Bn * Hn * Sn * Dn;   // outputs concatenated: (out, attn)

    // Out is accumulated via atomics across KSPLIT partials -> zero it first.
    hipMemsetAsync(d_out, 0, (size_t)Bn * Hn * Sn * Dn * sizeof(float), stream);

    attn_fused<<<dim3(Bn * (Sn / TQ) * KSPLIT), dim3(512), 0, stream>>>(q, k, v, out, attn);
}

// Round 2
// 940.607 us; speedup vs baseline: 1.1474x; 1.0282x over previous
//
#include <hip/hip_runtime.h>
#include <stdint.h>

// Problem constants (fixed by the reference).
#define Bn 2
#define Hn 16
#define Sn 2048
#define Dn 64
#define TQ 16                  // q rows per workgroup
#define KSPLIT 8               // k-range split across workgroups
#define KRANGE (Sn / KSPLIT)   // 256
#define KC 128                 // k columns per phase cycle (chunk)
#define NCHUNK (KRANGE / KC)   // 2
#define EPAD 136               // ebuf row length in shorts: 272 B = 17*16 -> b128-aligned, conflict-spread
#define DPAD 132               // den row length in floats: 528 B = 33*16 -> b128-aligned

typedef __attribute__((ext_vector_type(8))) short short8;
typedef __attribute__((ext_vector_type(4))) short short4v;
typedef __attribute__((ext_vector_type(4))) float float4v;

__device__ __forceinline__ short f2bf(float f) {
    uint32_t u = __builtin_bit_cast(uint32_t, f);
    u += 0x7fffu + ((u >> 16) & 1u);   // round-to-nearest-even
    return (short)(u >> 16);
}
__device__ __forceinline__ float bf2f(short s) {
    uint32_t u = ((uint32_t)(uint16_t)s) << 16;
    return __builtin_bit_cast(float, u);
}
// Load 8 consecutive fp32, convert to a bf16x8 MFMA fragment.
__device__ __forceinline__ short8 load_bf8(const float* p) {
    float4v a = *(const float4v*)p;
    float4v b = *(const float4v*)(p + 4);
    short8 r;
    r[0] = f2bf(a[0]); r[1] = f2bf(a[1]); r[2] = f2bf(a[2]); r[3] = f2bf(a[3]);
    r[4] = f2bf(b[0]); r[5] = f2bf(b[1]); r[6] = f2bf(b[2]); r[7] = f2bf(b[3]);
    return r;
}

#define MFMA(a, b, c) __builtin_amdgcn_mfma_f32_16x16x32_bf16((a), (b), (c), 0, 0, 0)
#define EXP2S 0.18033688011112042f   // log2(e) / 8: exp(s/8) == exp2(s * EXP2S)

// Grid: 2048 blocks of 512 threads. Block = 8 waves; wave w owns heads {2w,2w+1}
// for a 16-row q tile and a 256-wide k range (KSPLIT=8), processed in 2 chunks
// of 128 k. Per chunk, THREE barrier-free phases separated by 2 barriers:
//   phase1 : QK^T + exp -> bf16 ebuf[h][q][k]   (wave-private head rows)
//   phase2a: den[q][k] = sum over 16 heads      (cross-wave, after barrier)
//   phase2b: attn = e/den -> NT store; PV MFMA  (ebuf row IS the PV A-frag)
// 4 barriers/block total (was 16). No barrier at chunk end: next phase1 touches
// only own-head ebuf rows (ordered in-program), and den writes of chunk i+1 sit
// behind barrier #(2i+3) which all waves (hence all chunk-i phase2b work) passed.
__global__ __launch_bounds__(512, 4) void attn_fused(
    const float* __restrict__ Q, const float* __restrict__ K,
    const float* __restrict__ V, float* __restrict__ Out,
    float* __restrict__ Attn)
{
    // LDS: 16*16*136*2 + 16*132*4 = 69632 + 8448 = 78080 B  -> 2 blocks/CU
    __shared__ short ebuf[Hn][TQ][EPAD];   // e = exp(score/8), bf16, [head][q][k+pad]
    __shared__ float den[TQ][DPAD];        // softmax denominators, [q][k+pad]

    // Bijective XCD swizzle (2048 = 8 * 256): each XCD gets a contiguous chunk
    // of qb values sharing (b,ks) -> K/V panel L2 reuse.
    const int bid0 = blockIdx.x;
    const int bid  = (bid0 & 7) * 256 + (bid0 >> 3);

    const int qb = bid & 127;
    const int t2 = bid >> 7;
    const int ks = t2 & 7;
    const int b  = t2 >> 3;

    const int tid  = threadIdx.x;
    const int wave = tid >> 6;
    const int lane = tid & 63;
    const int quad = lane >> 4;
    const int l16  = lane & 15;

    const int h0 = wave * 2;
    const int q0 = qb * TQ;
    const int k0 = ks * KRANGE;

    // Resident Q fragments: A[m=l16][kdim=quad*8+j] per (head, d-chunk of 32).
    short8 aq[2][2];
#pragma unroll
    for (int hi = 0; hi < 2; ++hi) {
        const float* qp = Q + ((size_t)(b * Hn + h0 + hi) * Sn + (size_t)(q0 + l16)) * Dn
                            + quad * 8;
        aq[hi][0] = load_bf8(qp);
        aq[hi][1] = load_bf8(qp + 32);
    }

    // Out accumulators: [head][d-chunk] 16x16 C-frags.
    float4v acc[2][4];
#pragma unroll
    for (int hi = 0; hi < 2; ++hi)
#pragma unroll
        for (int dc = 0; dc < 4; ++dc)
            acc[hi][dc] = (float4v){0.f, 0.f, 0.f, 0.f};

    for (int chunk = 0; chunk < NCHUNK; ++chunk) {
        const int kb = k0 + chunk * KC;

        // ---- phase 1: QK^T + exp for own 2 heads, 8 independent k-tiles ----
#pragma unroll
        for (int hi = 0; hi < 2; ++hi) {
            const int h = h0 + hi;
            const float* kbase = K + (size_t)(b * Hn + h) * Sn * Dn;
#pragma unroll
            for (int kt = 0; kt < KC / 16; ++kt) {
                const float* kp = kbase + (size_t)(kb + kt * 16 + l16) * Dn + quad * 8;
                short8 bk0 = load_bf8(kp);
                short8 bk1 = load_bf8(kp + 32);
                float4v c = (float4v){0.f, 0.f, 0.f, 0.f};
                c = MFMA(aq[hi][0], bk0, c);
                c = MFMA(aq[hi][1], bk1, c);
                // C-layout: lane holds (q = quad*4+r, k = kt*16+l16).
#pragma unroll
                for (int r = 0; r < 4; ++r)
                    ebuf[h][quad * 4 + r][kt * 16 + l16] =
                        f2bf(__builtin_amdgcn_exp2f(c[r] * EXP2S));
            }
        }
        __syncthreads();   // [A] publish ebuf

        // ---- phase 2a: den[q][k] = sum over 16 heads (512 thr x 4 k each) ----
        {
            const int q  = tid >> 5;          // 0..15
            const int k4 = (tid & 31) * 4;    // 0..124
            float4v s = (float4v){0.f, 0.f, 0.f, 0.f};
#pragma unroll
            for (int h = 0; h < Hn; ++h) {
                short4v v4 = *(const short4v*)&ebuf[h][q][k4];
                s[0] += bf2f(v4[0]); s[1] += bf2f(v4[1]);
                s[2] += bf2f(v4[2]); s[3] += bf2f(v4[3]);
            }
            *(float4v*)&den[q][k4] = s;
        }
        __syncthreads();   // [B] publish den

        // ---- phase 2b: attn = e/den -> NT store; PV (no barriers) ----
#pragma unroll
        for (int c2 = 0; c2 < KC / 32; ++c2) {
            const int kk = c2 * 32 + quad * 8;   // this lane's 8-col window
            float4v dA = *(const float4v*)&den[l16][kk];
            float4v dB = *(const float4v*)&den[l16][kk + 4];
            float rc[8];
#pragma unroll
            for (int j = 0; j < 4; ++j) {
                rc[j]     = __builtin_amdgcn_rcpf(dA[j]);
                rc[4 + j] = __builtin_amdgcn_rcpf(dB[j]);
            }
#pragma unroll
            for (int hi = 0; hi < 2; ++hi) {
                const int h = h0 + hi;
                // ebuf row = PV A-frag: A[m=l16][kslot=quad*8+j], one b128.
                short8 ef = *(const short8*)&ebuf[h][l16][kk];
                float4v a0, a1;
#pragma unroll
                for (int j = 0; j < 4; ++j) {
                    a0[j] = bf2f(ef[j])     * rc[j];
                    a1[j] = bf2f(ef[4 + j]) * rc[4 + j];
                }
                // attn store: lane writes 32B contiguous (row q0+l16, cols kb+kk..+7)
                float* ap = Attn + ((size_t)(b * Hn + h) * Sn + (size_t)(q0 + l16)) * Sn
                            + kb + kk;
                __builtin_nontemporal_store(a0, (float4v*)ap);
                __builtin_nontemporal_store(a1, (float4v*)ap + 1);
                short8 av;
#pragma unroll
                for (int j = 0; j < 4; ++j) { av[j] = f2bf(a0[j]); av[4 + j] = f2bf(a1[j]); }
                // V B-frag: B[kslot=quad*8+j][n=dc*16+l16], physical k = kb+kk+j.
                const float* vbase = V + ((size_t)(b * Hn + h) * Sn + (size_t)(kb + kk)) * Dn;
#pragma unroll
                for (int dc = 0; dc < 4; ++dc) {
                    short8 bv;
#pragma unroll
                    for (int j = 0; j < 8; ++j)
                        bv[j] = f2bf(vbase[(size_t)j * Dn + dc * 16 + l16]);
                    acc[hi][dc] = MFMA(av, bv, acc[hi][dc]);
                }
            }
        }
        // no barrier here (see header comment)
    }

    // --- epilogue: atomic-accumulate the k-split partials into Out ---
#pragma unroll
    for (int hi = 0; hi < 2; ++hi)
#pragma unroll
        for (int dc = 0; dc < 4; ++dc) {
            float* op = Out + ((size_t)(b * Hn + h0 + hi) * Sn + (size_t)(q0 + quad * 4)) * Dn
                        + dc * 16 + l16;
#pragma unroll
            for (int r = 0; r < 4; ++r)
                unsafeAtomicAdd(op + (size_t)r * Dn, acc[hi][dc][r]);
        }
}

extern "C" void kernel_launch(void* const* d_in, const int* in_sizes, int n_in,
                              void* d_out, int out_size, void* d_ws, size_t ws_size,
                              hipStream_t stream) {
    const float* q = (const float*)d_in[0];
    const float* k = (const float*)d_in[1];
    const float* v = (const float*)d_in[2];
    float* out  = (float*)d_out;
    float* attn = out + (size_t)Bn * Hn * Sn * Dn;   // outputs concatenated: (out, attn)

    // Out is accumulated via atomics across KSPLIT partials -> zero it first.
    hipMemsetAsync(d_out, 0, (size_t)Bn * Hn * Sn * Dn * sizeof(float), stream);

    attn_fused<<<dim3(Bn * (Sn / TQ) * KSPLIT), dim3(512), 0, stream>>>(q, k, v, out, attn);
}